// Round 6
// baseline (82.843 us; speedup 1.0000x reference)
//
#include <hip/hip_runtime.h>
#include <hip/hip_bf16.h>

// AggregationLoss. preds [32,6,256,256] f32, targets [32,2,256,256] i32.
// sim = preds[:,2:6]; text = targets[:,0]; kernel = targets[:,1]; MAX_T=16.
// Per sample: G[t] = mean of sim over kernel==t; per-pixel
// loss = log1p(max(||sim_p - G[text_p]|| - 0.5, 0)^2); per-instance mean over
// text==t for valid t (t>=1, k_cnt>0, t_cnt>0); output = mean over valid.
//
// R6: R3 structure (best known: 50us) with three fixes:
//  - NB 16->32: 4 blocks/CU, 16 waves/CU (2x TLP; R3/R5 ran 8 waves/CU)
//  - DPP wave-reduce (row_shr 1/2/4/8 + row_bcast15/31, VALU pipe) replaces
//    the 450-ds_bpermute shfl butterfly (LDS-pipe hog, ~17us/CU in R3)
//  - int-packed counts (kcnt | tcnt<<16): 15 VGPRs, no SALU/ballot hazards
//    (R5 lesson: ballot + big-LDS transpose = spills + occupancy loss)

#define P_PIX 65536
#define NS 32
#define NB 32              // blocks per sample; grid = 1024 = 4 blocks/CU
#define SP_F 96            // stats partial stride: kcnt[0..14] ksum[15..74] tcnt[75..89]
#define WS_STATS_OFF 0
#define WS_ISUM_OFF (NS * NB * SP_F)   // isum partials: [NS][NB][16]

// ---- DPP wave(64) sum: result lands in lane 63 ----
template <int CTRL, int RM>
__device__ __forceinline__ float dpp_mov_f(float v) {
    return __int_as_float(
        __builtin_amdgcn_update_dpp(0, __float_as_int(v), CTRL, RM, 0xf, true));
}
template <int CTRL, int RM>
__device__ __forceinline__ int dpp_mov_i(int v) {
    return __builtin_amdgcn_update_dpp(0, v, CTRL, RM, 0xf, true);
}
__device__ __forceinline__ float wave_sum_f(float v) {
    v += dpp_mov_f<0x111, 0xf>(v);   // row_shr:1
    v += dpp_mov_f<0x112, 0xf>(v);   // row_shr:2
    v += dpp_mov_f<0x114, 0xf>(v);   // row_shr:4
    v += dpp_mov_f<0x118, 0xf>(v);   // row_shr:8  -> lane15 of each row = row sum
    v += dpp_mov_f<0x142, 0xa>(v);   // row_bcast15 (rows 1,3)
    v += dpp_mov_f<0x143, 0xc>(v);   // row_bcast31 (rows 2,3) -> lane63 = total
    return v;
}
__device__ __forceinline__ int wave_sum_i(int v) {
    v += dpp_mov_i<0x111, 0xf>(v);
    v += dpp_mov_i<0x112, 0xf>(v);
    v += dpp_mov_i<0x114, 0xf>(v);
    v += dpp_mov_i<0x118, 0xf>(v);
    v += dpp_mov_i<0x142, 0xa>(v);
    v += dpp_mov_i<0x143, 0xc>(v);
    return v;
}

__global__ __launch_bounds__(256, 4) void agg_stats_kernel(
        const float* __restrict__ preds,
        const int* __restrict__ targets,
        float* __restrict__ ws) {
    const int s = blockIdx.y;
    const int b = blockIdx.x;
    const int tid = threadIdx.x;
    const int lane = tid & 63;
    const int w = tid >> 6;

    float ksum[60];
    #pragma unroll
    for (int k = 0; k < 60; ++k) ksum[k] = 0.0f;
    int cnt[15];               // kcnt low16 | tcnt high16 (block-local <= 2048)
    #pragma unroll
    for (int k = 0; k < 15; ++k) cnt[k] = 0;

    const float* sim  = preds + (size_t)s * 6 * P_PIX + 2 * (size_t)P_PIX;
    const int*   text = targets + (size_t)s * 2 * P_PIX;
    const int*   kern = text + P_PIX;

    #pragma unroll
    for (int it = 0; it < 2; ++it) {
        const int p4 = b * 512 + it * 256 + tid;    // float4 index
        const int4   tb4 = ((const int4*)text)[p4];
        const int4   kb4 = ((const int4*)kern)[p4];
        const float4 v0 = ((const float4*)(sim))[p4];
        const float4 v1 = ((const float4*)(sim + P_PIX))[p4];
        const float4 v2 = ((const float4*)(sim + 2 * P_PIX))[p4];
        const float4 v3 = ((const float4*)(sim + 3 * P_PIX))[p4];
        const int tbv[4] = {tb4.x, tb4.y, tb4.z, tb4.w};
        const int kbv[4] = {kb4.x, kb4.y, kb4.z, kb4.w};
        const float a[4][4] = {{v0.x, v1.x, v2.x, v3.x}, {v0.y, v1.y, v2.y, v3.y},
                               {v0.z, v1.z, v2.z, v3.z}, {v0.w, v1.w, v2.w, v3.w}};
        #pragma unroll
        for (int j = 0; j < 4; ++j) {
            const int kb = kbv[j], tb = tbv[j];
            #pragma unroll
            for (int t = 1; t < 16; ++t) {
                const bool pk = (kb == t);
                cnt[t - 1] += (pk ? 1 : 0) + ((tb == t) ? 0x10000 : 0);
                const float m = pk ? 1.0f : 0.0f;
                #pragma unroll
                for (int c = 0; c < 4; ++c)
                    ksum[(t - 1) * 4 + c] = fmaf(m, a[j][c], ksum[(t - 1) * 4 + c]);
            }
        }
    }

    // ---- wave reduce via DPP (VALU pipe), lane 63 holds wave totals ----
    #pragma unroll
    for (int k = 0; k < 60; ++k) ksum[k] = wave_sum_f(ksum[k]);
    #pragma unroll
    for (int k = 0; k < 15; ++k) cnt[k] = wave_sum_i(cnt[k]);

    __shared__ float wsum[4][60];
    __shared__ int   wcnt[4][15];
    if (lane == 63) {
        #pragma unroll
        for (int k = 0; k < 60; ++k) wsum[w][k] = ksum[k];
        #pragma unroll
        for (int k = 0; k < 15; ++k) wcnt[w][k] = cnt[k];
    }
    __syncthreads();

    float* part = ws + WS_STATS_OFF + (size_t)(s * NB + b) * SP_F;
    if (tid < 60) {
        part[15 + tid] = (wsum[0][tid] + wsum[1][tid]) + (wsum[2][tid] + wsum[3][tid]);
    } else if (tid >= 64 && tid < 79) {
        const int k = tid - 64;
        const int ctot = (wcnt[0][k] + wcnt[1][k]) + (wcnt[2][k] + wcnt[3][k]);
        part[k] = (float)(ctot & 0xffff);
        part[75 + k] = (float)(((unsigned)ctot) >> 16);
    }
}

__global__ __launch_bounds__(256, 4) void agg_loss_kernel(
        const float* __restrict__ preds,
        const int* __restrict__ targets,
        float* __restrict__ ws) {
    const int s = blockIdx.y;
    const int b = blockIdx.x;
    const int tid = threadIdx.x;
    const int lane = tid & 63;
    const int w = tid >> 6;

    __shared__ float tmp[90];
    __shared__ __align__(16) float G4[16][4];   // G4[0] = 0 (background dummy)
    if (tid < 90) {
        const float* base = ws + WS_STATS_OFF + (size_t)s * NB * SP_F + tid;
        float v = 0.0f;
        #pragma unroll 8
        for (int pb = 0; pb < NB; ++pb) v += base[pb * SP_F];
        tmp[tid] = v;
    }
    __syncthreads();
    if (tid < 60) G4[1 + (tid >> 2)][tid & 3] = tmp[15 + tid] / fmaxf(tmp[tid >> 2], 1.0f);
    if (tid >= 64 && tid < 68) G4[0][tid - 64] = 0.0f;
    __syncthreads();

    float isum[15];
    #pragma unroll
    for (int k = 0; k < 15; ++k) isum[k] = 0.0f;

    const float* sim  = preds + (size_t)s * 6 * P_PIX + 2 * (size_t)P_PIX;
    const int*   text = targets + (size_t)s * 2 * P_PIX;

    #pragma unroll
    for (int it = 0; it < 2; ++it) {
        const int p4 = b * 512 + it * 256 + tid;
        const int4   tb4 = ((const int4*)text)[p4];
        const float4 v0 = ((const float4*)(sim))[p4];
        const float4 v1 = ((const float4*)(sim + P_PIX))[p4];
        const float4 v2 = ((const float4*)(sim + 2 * P_PIX))[p4];
        const float4 v3 = ((const float4*)(sim + 3 * P_PIX))[p4];
        const int tbv[4] = {tb4.x, tb4.y, tb4.z, tb4.w};
        const float a[4][4] = {{v0.x, v1.x, v2.x, v3.x}, {v0.y, v1.y, v2.y, v3.y},
                               {v0.z, v1.z, v2.z, v3.z}, {v0.w, v1.w, v2.w, v3.w}};
        #pragma unroll
        for (int j = 0; j < 4; ++j) {
            const int tb = tbv[j];
            const float4 g = *(const float4*)G4[tb];
            const float d0 = a[j][0] - g.x;
            const float d1 = a[j][1] - g.y;
            const float d2 = a[j][2] - g.z;
            const float d3 = a[j][3] - g.w;
            const float dd = sqrtf(d0 * d0 + d1 * d1 + d2 * d2 + d3 * d3) - 0.5f;
            const float r = fmaxf(dd, 0.0f);
            const float lp = log1pf(r * r);
            #pragma unroll
            for (int t = 1; t < 16; ++t) isum[t - 1] += (tb == t) ? lp : 0.0f;
        }
    }

    #pragma unroll
    for (int k = 0; k < 15; ++k) isum[k] = wave_sum_f(isum[k]);

    __shared__ float iw[4][15];
    if (lane == 63) {
        #pragma unroll
        for (int k = 0; k < 15; ++k) iw[w][k] = isum[k];
    }
    __syncthreads();
    if (tid < 15) {
        ws[WS_ISUM_OFF + (size_t)(s * NB + b) * 16 + tid] =
            (iw[0][tid] + iw[1][tid]) + (iw[2][tid] + iw[3][tid]);
    }
}

__global__ __launch_bounds__(512) void agg_finalize_kernel(
        const float* __restrict__ ws, float* __restrict__ out) {
    const int tid = threadIdx.x;       // 512 = 32 samples * 16 lanes
    const int s = tid >> 4;
    const int t = tid & 15;            // bin index - 1; lane 15 inactive
    float kc = 0.0f, tc = 0.0f, is = 0.0f;
    if (t < 15) {
        #pragma unroll 8
        for (int pb = 0; pb < NB; ++pb) {
            const float* st = ws + WS_STATS_OFF + (size_t)(s * NB + pb) * SP_F;
            kc += st[t];
            tc += st[75 + t];
            is += ws[WS_ISUM_OFF + (size_t)(s * NB + pb) * 16 + t];
        }
    }
    const bool valid = (t < 15) && (kc > 0.0f) && (tc > 0.0f);
    float im = valid ? is / tc : 0.0f;
    float nv = valid ? 1.0f : 0.0f;
    #pragma unroll
    for (int m = 8; m >= 1; m >>= 1) {
        im += __shfl_xor(im, m, 16);
        nv += __shfl_xor(nv, m, 16);
    }
    if (t == 0) out[s] = (nv > 0.0f) ? (im / nv) : 0.0f;
}

extern "C" void kernel_launch(void* const* d_in, const int* in_sizes, int n_in,
                              void* d_out, int out_size, void* d_ws, size_t ws_size,
                              hipStream_t stream) {
    const float* preds = (const float*)d_in[0];
    const int* targets = (const int*)d_in[1];
    float* out = (float*)d_out;
    float* ws = (float*)d_ws;

    dim3 grid(NB, NS);
    agg_stats_kernel<<<grid, 256, 0, stream>>>(preds, targets, ws);
    agg_loss_kernel<<<grid, 256, 0, stream>>>(preds, targets, ws);
    agg_finalize_kernel<<<1, 512, 0, stream>>>(ws, out);
}

// Round 7
// 43.791 us; speedup vs baseline: 1.8918x; 1.8918x over previous
//
#include <hip/hip_runtime.h>
#include <hip/hip_bf16.h>

// AggregationLoss. preds [32,6,256,256] f32, targets [32,2,256,256] i32.
// sim = preds[:,2:6]; text = targets[:,0]; kernel = targets[:,1]; MAX_T=16.
// Per sample: G[t] = mean of sim over kernel==t; per-pixel
// loss = log1p(max(||sim_p - G[text_p]|| - 0.5, 0)^2); per-instance mean over
// text==t for valid t (t>=1, k_cnt>0, t_cnt>0); output = mean over valid.
//
// R7 = R6 minus the VGPR cap. R6 post-mortem: __launch_bounds__(256,4)
// forced a 64-VGPR target on a kernel with ~110 live values -> 63 MB of
// scratch spill WRITE per dispatch (167 MB total W, 96 MB F). NEVER set the
// min-waves arg on a fat-accumulator kernel. R3 (no min-waves) never spilled.
// Keep: DPP wave-reduce (VALU pipe), packed int counts, NB=32 TLP.

#define P_PIX 65536
#define NS 32
#define NB 32              // blocks per sample; grid = 1024 = 4 blocks/CU
#define SP_F 96            // stats partial stride: kcnt[0..14] ksum[15..74] tcnt[75..89]
#define WS_STATS_OFF 0
#define WS_ISUM_OFF (NS * NB * SP_F)   // isum partials: [NS][NB][16]

// ---- DPP wave(64) sum: result lands in lane 63 ----
template <int CTRL, int RM>
__device__ __forceinline__ float dpp_mov_f(float v) {
    return __int_as_float(
        __builtin_amdgcn_update_dpp(0, __float_as_int(v), CTRL, RM, 0xf, true));
}
template <int CTRL, int RM>
__device__ __forceinline__ int dpp_mov_i(int v) {
    return __builtin_amdgcn_update_dpp(0, v, CTRL, RM, 0xf, true);
}
__device__ __forceinline__ float wave_sum_f(float v) {
    v += dpp_mov_f<0x111, 0xf>(v);   // row_shr:1
    v += dpp_mov_f<0x112, 0xf>(v);   // row_shr:2
    v += dpp_mov_f<0x114, 0xf>(v);   // row_shr:4
    v += dpp_mov_f<0x118, 0xf>(v);   // row_shr:8  -> lane15 of each row = row sum
    v += dpp_mov_f<0x142, 0xa>(v);   // row_bcast15 (rows 1,3)
    v += dpp_mov_f<0x143, 0xc>(v);   // row_bcast31 (rows 2,3) -> lane63 = total
    return v;
}
__device__ __forceinline__ int wave_sum_i(int v) {
    v += dpp_mov_i<0x111, 0xf>(v);
    v += dpp_mov_i<0x112, 0xf>(v);
    v += dpp_mov_i<0x114, 0xf>(v);
    v += dpp_mov_i<0x118, 0xf>(v);
    v += dpp_mov_i<0x142, 0xa>(v);
    v += dpp_mov_i<0x143, 0xc>(v);
    return v;
}

__global__ __launch_bounds__(256) void agg_stats_kernel(
        const float* __restrict__ preds,
        const int* __restrict__ targets,
        float* __restrict__ ws) {
    const int s = blockIdx.y;
    const int b = blockIdx.x;
    const int tid = threadIdx.x;
    const int lane = tid & 63;
    const int w = tid >> 6;

    float ksum[60];
    #pragma unroll
    for (int k = 0; k < 60; ++k) ksum[k] = 0.0f;
    int cnt[15];               // kcnt low16 | tcnt high16 (block-local <= 2048)
    #pragma unroll
    for (int k = 0; k < 15; ++k) cnt[k] = 0;

    const float* sim  = preds + (size_t)s * 6 * P_PIX + 2 * (size_t)P_PIX;
    const int*   text = targets + (size_t)s * 2 * P_PIX;
    const int*   kern = text + P_PIX;

    #pragma unroll
    for (int it = 0; it < 2; ++it) {
        const int p4 = b * 512 + it * 256 + tid;    // float4 index
        const int4   tb4 = ((const int4*)text)[p4];
        const int4   kb4 = ((const int4*)kern)[p4];
        const float4 v0 = ((const float4*)(sim))[p4];
        const float4 v1 = ((const float4*)(sim + P_PIX))[p4];
        const float4 v2 = ((const float4*)(sim + 2 * P_PIX))[p4];
        const float4 v3 = ((const float4*)(sim + 3 * P_PIX))[p4];
        const int tbv[4] = {tb4.x, tb4.y, tb4.z, tb4.w};
        const int kbv[4] = {kb4.x, kb4.y, kb4.z, kb4.w};
        const float a[4][4] = {{v0.x, v1.x, v2.x, v3.x}, {v0.y, v1.y, v2.y, v3.y},
                               {v0.z, v1.z, v2.z, v3.z}, {v0.w, v1.w, v2.w, v3.w}};
        #pragma unroll
        for (int j = 0; j < 4; ++j) {
            const int kb = kbv[j], tb = tbv[j];
            #pragma unroll
            for (int t = 1; t < 16; ++t) {
                const bool pk = (kb == t);
                cnt[t - 1] += (pk ? 1 : 0) + ((tb == t) ? 0x10000 : 0);
                const float m = pk ? 1.0f : 0.0f;
                #pragma unroll
                for (int c = 0; c < 4; ++c)
                    ksum[(t - 1) * 4 + c] = fmaf(m, a[j][c], ksum[(t - 1) * 4 + c]);
            }
        }
    }

    // ---- wave reduce via DPP (VALU pipe), lane 63 holds wave totals ----
    #pragma unroll
    for (int k = 0; k < 60; ++k) ksum[k] = wave_sum_f(ksum[k]);
    #pragma unroll
    for (int k = 0; k < 15; ++k) cnt[k] = wave_sum_i(cnt[k]);

    __shared__ float wsum[4][60];
    __shared__ int   wcnt[4][15];
    if (lane == 63) {
        #pragma unroll
        for (int k = 0; k < 60; ++k) wsum[w][k] = ksum[k];
        #pragma unroll
        for (int k = 0; k < 15; ++k) wcnt[w][k] = cnt[k];
    }
    __syncthreads();

    float* part = ws + WS_STATS_OFF + (size_t)(s * NB + b) * SP_F;
    if (tid < 60) {
        part[15 + tid] = (wsum[0][tid] + wsum[1][tid]) + (wsum[2][tid] + wsum[3][tid]);
    } else if (tid >= 64 && tid < 79) {
        const int k = tid - 64;
        const int ctot = (wcnt[0][k] + wcnt[1][k]) + (wcnt[2][k] + wcnt[3][k]);
        part[k] = (float)(ctot & 0xffff);
        part[75 + k] = (float)(((unsigned)ctot) >> 16);
    }
}

__global__ __launch_bounds__(256) void agg_loss_kernel(
        const float* __restrict__ preds,
        const int* __restrict__ targets,
        float* __restrict__ ws) {
    const int s = blockIdx.y;
    const int b = blockIdx.x;
    const int tid = threadIdx.x;
    const int lane = tid & 63;
    const int w = tid >> 6;

    __shared__ float tmp[90];
    __shared__ __align__(16) float G4[16][4];   // G4[0] = 0 (background dummy)
    if (tid < 90) {
        const float* base = ws + WS_STATS_OFF + (size_t)s * NB * SP_F + tid;
        float v = 0.0f;
        #pragma unroll 8
        for (int pb = 0; pb < NB; ++pb) v += base[pb * SP_F];
        tmp[tid] = v;
    }
    __syncthreads();
    if (tid < 60) G4[1 + (tid >> 2)][tid & 3] = tmp[15 + tid] / fmaxf(tmp[tid >> 2], 1.0f);
    if (tid >= 64 && tid < 68) G4[0][tid - 64] = 0.0f;
    __syncthreads();

    float isum[15];
    #pragma unroll
    for (int k = 0; k < 15; ++k) isum[k] = 0.0f;

    const float* sim  = preds + (size_t)s * 6 * P_PIX + 2 * (size_t)P_PIX;
    const int*   text = targets + (size_t)s * 2 * P_PIX;

    #pragma unroll
    for (int it = 0; it < 2; ++it) {
        const int p4 = b * 512 + it * 256 + tid;
        const int4   tb4 = ((const int4*)text)[p4];
        const float4 v0 = ((const float4*)(sim))[p4];
        const float4 v1 = ((const float4*)(sim + P_PIX))[p4];
        const float4 v2 = ((const float4*)(sim + 2 * P_PIX))[p4];
        const float4 v3 = ((const float4*)(sim + 3 * P_PIX))[p4];
        const int tbv[4] = {tb4.x, tb4.y, tb4.z, tb4.w};
        const float a[4][4] = {{v0.x, v1.x, v2.x, v3.x}, {v0.y, v1.y, v2.y, v3.y},
                               {v0.z, v1.z, v2.z, v3.z}, {v0.w, v1.w, v2.w, v3.w}};
        #pragma unroll
        for (int j = 0; j < 4; ++j) {
            const int tb = tbv[j];
            const float4 g = *(const float4*)G4[tb];
            const float d0 = a[j][0] - g.x;
            const float d1 = a[j][1] - g.y;
            const float d2 = a[j][2] - g.z;
            const float d3 = a[j][3] - g.w;
            const float dd = sqrtf(d0 * d0 + d1 * d1 + d2 * d2 + d3 * d3) - 0.5f;
            const float r = fmaxf(dd, 0.0f);
            const float lp = log1pf(r * r);
            #pragma unroll
            for (int t = 1; t < 16; ++t) isum[t - 1] += (tb == t) ? lp : 0.0f;
        }
    }

    #pragma unroll
    for (int k = 0; k < 15; ++k) isum[k] = wave_sum_f(isum[k]);

    __shared__ float iw[4][15];
    if (lane == 63) {
        #pragma unroll
        for (int k = 0; k < 15; ++k) iw[w][k] = isum[k];
    }
    __syncthreads();
    if (tid < 15) {
        ws[WS_ISUM_OFF + (size_t)(s * NB + b) * 16 + tid] =
            (iw[0][tid] + iw[1][tid]) + (iw[2][tid] + iw[3][tid]);
    }
}

__global__ __launch_bounds__(512) void agg_finalize_kernel(
        const float* __restrict__ ws, float* __restrict__ out) {
    const int tid = threadIdx.x;       // 512 = 32 samples * 16 lanes
    const int s = tid >> 4;
    const int t = tid & 15;            // bin index - 1; lane 15 inactive
    float kc = 0.0f, tc = 0.0f, is = 0.0f;
    if (t < 15) {
        #pragma unroll 8
        for (int pb = 0; pb < NB; ++pb) {
            const float* st = ws + WS_STATS_OFF + (size_t)(s * NB + pb) * SP_F;
            kc += st[t];
            tc += st[75 + t];
            is += ws[WS_ISUM_OFF + (size_t)(s * NB + pb) * 16 + t];
        }
    }
    const bool valid = (t < 15) && (kc > 0.0f) && (tc > 0.0f);
    float im = valid ? is / tc : 0.0f;
    float nv = valid ? 1.0f : 0.0f;
    #pragma unroll
    for (int m = 8; m >= 1; m >>= 1) {
        im += __shfl_xor(im, m, 16);
        nv += __shfl_xor(nv, m, 16);
    }
    if (t == 0) out[s] = (nv > 0.0f) ? (im / nv) : 0.0f;
}

extern "C" void kernel_launch(void* const* d_in, const int* in_sizes, int n_in,
                              void* d_out, int out_size, void* d_ws, size_t ws_size,
                              hipStream_t stream) {
    const float* preds = (const float*)d_in[0];
    const int* targets = (const int*)d_in[1];
    float* out = (float*)d_out;
    float* ws = (float*)d_ws;

    dim3 grid(NB, NS);
    agg_stats_kernel<<<grid, 256, 0, stream>>>(preds, targets, ws);
    agg_loss_kernel<<<grid, 256, 0, stream>>>(preds, targets, ws);
    agg_finalize_kernel<<<1, 512, 0, stream>>>(ws, out);
}